// Round 1
// baseline (1759.935 us; speedup 1.0000x reference)
//
#include <hip/hip_runtime.h>
#include <cstddef>

// Problem constants
#define B_   8
#define C4_  256
#define C5_  512
#define OC_  256
#define FR_  128
#define SIM_ 64
#define H_   64
#define W_   64
#define HW_  4096

// ---------------------------------------------------------------------------
// Kernel A: fused = conv3x3(c4, w3, pad=1) + conv1x1(c5_up, w1)
// grid (OC/32, H/4, B), block 256
// ---------------------------------------------------------------------------
__global__ __launch_bounds__(256) void fuse_conv(
    const float* __restrict__ c4, const float* __restrict__ c5,
    const float* __restrict__ w3, const float* __restrict__ w1,
    float* __restrict__ fused)
{
    __shared__ float sIn[6][66];
    __shared__ float sC5[2][4][64];
    __shared__ float sW3[32][9];
    __shared__ float sW1[32][2];

    const int t   = threadIdx.x;
    const int b   = blockIdx.z;
    const int r0  = blockIdx.y * 4;
    const int oc0 = blockIdx.x * 32;

    const int og  = t >> 5;        // 0..7  -> 4 ocs each
    const int pg  = t & 31;        // 0..31 -> 8 px each
    const int row = pg >> 3;       // 0..3
    const int cs  = (pg & 7) * 8;  // 0..56

    float acc[4][8];
    #pragma unroll
    for (int o = 0; o < 4; ++o)
        #pragma unroll
        for (int p = 0; p < 8; ++p) acc[o][p] = 0.f;

    for (int c = 0; c < C4_; ++c) {
        __syncthreads();
        // stage c4 tile: rows r0-1..r0+4, cols -1..64 (zero pad)
        for (int idx = t; idx < 396; idx += 256) {
            int rr = idx / 66, cl = idx % 66;
            int gh = r0 - 1 + rr, gw = cl - 1;
            float v = 0.f;
            if (gh >= 0 && gh < H_ && gw >= 0 && gw < W_)
                v = c4[(((size_t)b * C4_ + c) * H_ + gh) * W_ + gw];
            sIn[rr][cl] = v;
        }
        // stage c5_up tile for channels 2c, 2c+1
        for (int idx = t; idx < 512; idx += 256) {
            int cc = idx >> 8, rem = idx & 255, rr = rem >> 6, wc = rem & 63;
            sC5[cc][rr][wc] =
                c5[(((size_t)b * C5_ + 2 * c + cc) * 32 + ((r0 + rr) >> 1)) * 32 + (wc >> 1)];
        }
        // stage weights
        for (int idx = t; idx < 288; idx += 256) {
            int o = idx / 9, k = idx % 9;
            sW3[o][k] = w3[(((size_t)(oc0 + o)) * C4_ + c) * 9 + k];
        }
        if (t < 64) {
            int o = t >> 1, cc = t & 1;
            sW1[o][cc] = w1[((size_t)(oc0 + o)) * C5_ + 2 * c + cc];
        }
        __syncthreads();

        float vin[3][10];
        #pragma unroll
        for (int dr = 0; dr < 3; ++dr)
            #pragma unroll
            for (int dc = 0; dc < 10; ++dc)
                vin[dr][dc] = sIn[row + dr][cs + dc];
        float v5[2][8];
        #pragma unroll
        for (int cc = 0; cc < 2; ++cc)
            #pragma unroll
            for (int p = 0; p < 8; ++p)
                v5[cc][p] = sC5[cc][row][cs + p];

        #pragma unroll
        for (int o = 0; o < 4; ++o) {
            const int ol = og * 4 + o;
            float wv[9];
            #pragma unroll
            for (int k = 0; k < 9; ++k) wv[k] = sW3[ol][k];
            const float u0 = sW1[ol][0], u1 = sW1[ol][1];
            #pragma unroll
            for (int p = 0; p < 8; ++p) {
                float s = acc[o][p];
                s += wv[0] * vin[0][p] + wv[1] * vin[0][p + 1] + wv[2] * vin[0][p + 2];
                s += wv[3] * vin[1][p] + wv[4] * vin[1][p + 1] + wv[5] * vin[1][p + 2];
                s += wv[6] * vin[2][p] + wv[7] * vin[2][p + 1] + wv[8] * vin[2][p + 2];
                s += u0 * v5[0][p] + u1 * v5[1][p];
                acc[o][p] = s;
            }
        }
    }

    #pragma unroll
    for (int o = 0; o < 4; ++o) {
        size_t base = (((size_t)b * OC_ + oc0 + og * 4 + o) * H_ + r0 + row) * W_ + cs;
        float4 v0 = make_float4(acc[o][0], acc[o][1], acc[o][2], acc[o][3]);
        float4 v1 = make_float4(acc[o][4], acc[o][5], acc[o][6], acc[o][7]);
        *(float4*)&fused[base]     = v0;
        *(float4*)&fused[base + 4] = v1;
    }
}

// ---------------------------------------------------------------------------
// Generic tiled 1x1 conv: out[b,oc,hw] = sum_c w[oc,c] * in[b,c,hw]
// grid (Cout/64, H/4, B), block 256.  MODE 1: also accumulate BN sums.
// ---------------------------------------------------------------------------
template <int MODE>
__global__ __launch_bounds__(256) void conv1x1(
    const float* __restrict__ in, const float* __restrict__ w,
    float* __restrict__ out, int Cin, int Cout, float* __restrict__ sums)
{
    __shared__ float sF[8][256];
    __shared__ float sW[8][64];
    __shared__ float lsum[64], lsq[64];

    const int t   = threadIdx.x;
    const int b   = blockIdx.z;
    const int r0  = blockIdx.y * 4;
    const int oc0 = blockIdx.x * 64;

    const int og  = t >> 5;       // 0..7
    const int pg  = t & 31;       // 0..31
    const int ocl = og * 8;
    const int pxb = pg * 8;

    float acc[8][8];
    #pragma unroll
    for (int o = 0; o < 8; ++o)
        #pragma unroll
        for (int p = 0; p < 8; ++p) acc[o][p] = 0.f;

    const float* inb = in + (size_t)b * Cin * HW_ + r0 * W_;

    for (int c0 = 0; c0 < Cin; c0 += 8) {
        __syncthreads();
        for (int idx = t; idx < 2048; idx += 256) {
            int cc = idx >> 8, px = idx & 255;
            sF[cc][px] = inb[(size_t)(c0 + cc) * HW_ + px];
        }
        for (int idx = t; idx < 512; idx += 256) {
            int cc = idx >> 6, o = idx & 63;
            sW[cc][o] = w[(size_t)(oc0 + o) * Cin + c0 + cc];
        }
        __syncthreads();

        #pragma unroll
        for (int cc = 0; cc < 8; ++cc) {
            float f[8], ww[8];
            #pragma unroll
            for (int i = 0; i < 8; ++i) f[i] = sF[cc][pxb + i];
            #pragma unroll
            for (int i = 0; i < 8; ++i) ww[i] = sW[cc][ocl + i];
            #pragma unroll
            for (int o = 0; o < 8; ++o)
                #pragma unroll
                for (int p = 0; p < 8; ++p)
                    acc[o][p] += ww[o] * f[p];
        }
    }

    #pragma unroll
    for (int o = 0; o < 8; ++o) {
        size_t base = ((size_t)b * Cout + oc0 + ocl + o) * HW_ + r0 * W_ + pxb;
        float4 v0 = make_float4(acc[o][0], acc[o][1], acc[o][2], acc[o][3]);
        float4 v1 = make_float4(acc[o][4], acc[o][5], acc[o][6], acc[o][7]);
        *(float4*)&out[base]     = v0;
        *(float4*)&out[base + 4] = v1;
    }

    if (MODE == 1) {
        if (t < 64) { lsum[t] = 0.f; lsq[t] = 0.f; }
        __syncthreads();
        #pragma unroll
        for (int o = 0; o < 8; ++o) {
            float s = 0.f, q = 0.f;
            #pragma unroll
            for (int p = 0; p < 8; ++p) { s += acc[o][p]; q += acc[o][p] * acc[o][p]; }
            atomicAdd(&lsum[ocl + o], s);
            atomicAdd(&lsq[ocl + o], q);
        }
        __syncthreads();
        if (t < 64) {
            atomicAdd(&sums[oc0 + t], lsum[t]);
            atomicAdd(&sums[256 + oc0 + t], lsq[t]);
        }
    }
}

// ---------------------------------------------------------------------------
// BN finalize: a = gamma*rstd, b = beta - mu*a
// ---------------------------------------------------------------------------
__global__ void bn_finalize(const float* __restrict__ sums,
                            const float* __restrict__ gamma,
                            const float* __restrict__ beta,
                            float* __restrict__ ab)
{
    int c = threadIdx.x;
    const float n = (float)(B_ * HW_);
    float mu  = sums[c] / n;
    float var = sums[256 + c] / n - mu * mu;
    float a = gamma[c] * rsqrtf(var + 1e-5f);
    ab[c]       = a;
    ab[256 + c] = beta[c] - mu * a;
}

// ---------------------------------------------------------------------------
// X = silu(a*y + b), elementwise (may alias in==out), float4
// ---------------------------------------------------------------------------
__global__ __launch_bounds__(256) void silu_bn(const float* __restrict__ y,
                                               const float* __restrict__ ab,
                                               float* __restrict__ X)
{
    size_t i = (size_t)blockIdx.x * 256 + threadIdx.x;   // float4 index
    int c = (int)((i >> 10) & 255);
    float a = ab[c], bb = ab[256 + c];
    float4 v = ((const float4*)y)[i];
    float z;
    z = a * v.x + bb; v.x = z / (1.f + __expf(-z));
    z = a * v.y + bb; v.y = z / (1.f + __expf(-z));
    z = a * v.z + bb; v.z = z / (1.f + __expf(-z));
    z = a * v.w + bb; v.w = z / (1.f + __expf(-z));
    ((float4*)X)[i] = v;
}

// ---------------------------------------------------------------------------
// Adaptive avg pool to 3x3 (up=1: input is 32x32, nearest-upsampled view)
// grid (3, C/4, B), block 256 = 4ch x 64w
// ---------------------------------------------------------------------------
__global__ __launch_bounds__(256) void pool_kernel(const float* __restrict__ in,
                                                   float* __restrict__ out,
                                                   int C, int up)
{
    __shared__ float colsum[4][64];
    const int i = blockIdx.x, cg = blockIdx.y, b = blockIdx.z;
    const int t = threadIdx.x;
    const int ch = t >> 6, w = t & 63;
    const int c = cg * 4 + ch;
    const int h0 = (i * 64) / 3, h1 = ((i + 1) * 64 + 2) / 3;
    float s = 0.f;
    for (int h = h0; h < h1; ++h) {
        float v = up ? in[(((size_t)b * C + c) * 32 + (h >> 1)) * 32 + (w >> 1)]
                     : in[(((size_t)b * C + c) * 64 + h) * 64 + w];
        s += v;
    }
    colsum[ch][w] = s;
    __syncthreads();
    if (t < 12) {
        int c2 = t / 3, j = t % 3;
        int w0 = (j * 64) / 3, w1 = ((j + 1) * 64 + 2) / 3;
        float tot = 0.f;
        for (int x = w0; x < w1; ++x) tot += colsum[c2][x];
        out[(((size_t)b * C + cg * 4 + c2) * 3 + i) * 3 + j] =
            tot / (float)((h1 - h0) * (w1 - w0));
    }
}

// ---------------------------------------------------------------------------
// sim + gating MLP + softmax -> kernels[b, r, 9]
// grid (9, B), block 64
// ---------------------------------------------------------------------------
__global__ __launch_bounds__(64) void sim_mlp(
    const float* __restrict__ pool4, const float* __restrict__ pool5,
    const float* __restrict__ w4, const float* __restrict__ w5,
    const float* __restrict__ kgw1, const float* __restrict__ kgb1,
    const float* __restrict__ kgw2, const float* __restrict__ kgb2,
    const float* __restrict__ mask, float* __restrict__ kers)
{
    const int r = blockIdx.x, b = blockIdx.y, m = threadIdx.x;
    float p4 = 0.f, p5 = 0.f;
    for (int c = 0; c < C4_; ++c)
        p4 += w4[(size_t)m * C4_ + c] * pool4[((size_t)b * C4_ + c) * 9 + r];
    for (int c = 0; c < C5_; ++c)
        p5 += w5[(size_t)m * C5_ + c] * pool5[((size_t)b * C5_ + c) * 9 + r];
    float v = p4 * p5;
    #pragma unroll
    for (int off = 32; off; off >>= 1) v += __shfl_down(v, off);
    if (m == 0) {
        float g = v * (1.f / (1.f + __expf(-mask[r])));
        float hb[16];
        #pragma unroll
        for (int j = 0; j < 16; ++j) hb[j] = fmaxf(g * kgw1[j] + kgb1[j], 0.f);
        float lg[9], mx = -1e30f;
        #pragma unroll
        for (int k = 0; k < 9; ++k) {
            float s = kgb2[k];
            #pragma unroll
            for (int j = 0; j < 16; ++j) s += kgw2[k * 16 + j] * hb[j];
            lg[k] = s;
            mx = fmaxf(mx, s);
        }
        float den = 0.f;
        #pragma unroll
        for (int k = 0; k < 9; ++k) { lg[k] = __expf(lg[k] - mx); den += lg[k]; }
        float inv = 1.f / den;
        #pragma unroll
        for (int k = 0; k < 9; ++k)
            kers[((size_t)b * 9 + r) * 9 + k] = lg[k] * inv;
    }
}

// ---------------------------------------------------------------------------
// Dynamic 3x3 per-region conv: out += sum_k X[b,c,h+dy-1,w+dx-1]*K[b,region,k]
// grid (H/8, 256/4, B), block 256 = 4ch x 64w
// ---------------------------------------------------------------------------
__global__ __launch_bounds__(256) void dynconv(const float* __restrict__ X,
                                               const float* __restrict__ kers,
                                               float* __restrict__ out)
{
    __shared__ float sX[4][10][66];
    __shared__ float sK[81];
    const int t = threadIdx.x;
    const int r0 = blockIdx.x * 8, cg = blockIdx.y, b = blockIdx.z;
    const int ch = t >> 6, w = t & 63;
    const int c = cg * 4 + ch;

    for (int idx = t; idx < 2640; idx += 256) {
        int cc = idx / 660, rem = idx % 660, rr = rem / 66, cl = rem % 66;
        int gh = r0 - 1 + rr, gw = cl - 1;
        float v = 0.f;
        if (gh >= 0 && gh < H_ && gw >= 0 && gw < W_)
            v = X[(((size_t)b * 256 + cg * 4 + cc) * H_ + gh) * W_ + gw];
        sX[cc][rr][cl] = v;
    }
    if (t < 81) sK[t] = kers[(size_t)b * 81 + t];
    __syncthreads();

    const int rx = (w * 3) >> 6;
    for (int hh = 0; hh < 8; ++hh) {
        int h = r0 + hh;
        int ry = (h * 3) >> 6;
        const float* kp = &sK[(ry * 3 + rx) * 9];
        float acc = 0.f;
        #pragma unroll
        for (int dy = 0; dy < 3; ++dy)
            #pragma unroll
            for (int dx = 0; dx < 3; ++dx)
                acc += kp[dy * 3 + dx] * sX[ch][hh + dy][w + dx];
        size_t o = (((size_t)b * 256 + c) * H_ + h) * W_ + w;
        out[o] += acc;
    }
}

// ---------------------------------------------------------------------------
// Launch
// ---------------------------------------------------------------------------
extern "C" void kernel_launch(void* const* d_in, const int* in_sizes, int n_in,
                              void* d_out, int out_size, void* d_ws, size_t ws_size,
                              hipStream_t stream)
{
    const float* c4       = (const float*)d_in[0];
    const float* c5       = (const float*)d_in[1];
    const float* w_to_fuse= (const float*)d_in[2];
    const float* bn_gamma = (const float*)d_in[3];
    const float* bn_beta  = (const float*)d_in[4];
    const float* w_c4_proc= (const float*)d_in[5];
    const float* w_conv1  = (const float*)d_in[6];
    const float* w_reshape= (const float*)d_in[7];
    const float* w_proj   = (const float*)d_in[8];
    const float* w_sim4   = (const float*)d_in[9];
    const float* w_sim5   = (const float*)d_in[10];
    const float* kg_w1    = (const float*)d_in[11];
    const float* kg_b1    = (const float*)d_in[12];
    const float* kg_w2    = (const float*)d_in[13];
    const float* kg_b2    = (const float*)d_in[14];
    const float* mask_raw = (const float*)d_in[15];

    float* out = (float*)d_out;
    float* ws  = (float*)d_ws;

    const size_t nFused = (size_t)B_ * OC_ * HW_;      // 8388608
    float* fused = ws;
    float* yX    = fused + nFused;                     // y, then X in place
    float* tmp   = yX + nFused;                        // (B,128,64,64)
    float* pool4 = tmp + (size_t)B_ * FR_ * HW_;       // 8*256*9
    float* pool5 = pool4 + (size_t)B_ * C4_ * 9;       // 8*512*9
    float* sums  = pool5 + (size_t)B_ * C5_ * 9;       // 512
    float* ab    = sums + 512;                         // 512
    float* kers  = ab + 512;                           // 648

    hipMemsetAsync(sums, 0, 512 * sizeof(float), stream);

    fuse_conv<<<dim3(8, 16, 8), 256, 0, stream>>>(c4, c5, w_c4_proc, w_conv1, fused);

    conv1x1<1><<<dim3(4, 16, 8), 256, 0, stream>>>(fused, w_to_fuse, yX, 256, 256, sums);

    bn_finalize<<<1, 256, 0, stream>>>(sums, bn_gamma, bn_beta, ab);

    silu_bn<<<8192, 256, 0, stream>>>(yX, ab, yX);

    pool_kernel<<<dim3(3, 64, 8), 256, 0, stream>>>(c4, pool4, 256, 0);
    pool_kernel<<<dim3(3, 128, 8), 256, 0, stream>>>(c5, pool5, 512, 1);

    sim_mlp<<<dim3(9, 8), 64, 0, stream>>>(pool4, pool5, w_sim4, w_sim5,
                                           kg_w1, kg_b1, kg_w2, kg_b2,
                                           mask_raw, kers);

    conv1x1<0><<<dim3(2, 16, 8), 256, 0, stream>>>(fused, w_reshape, tmp, 256, 128, nullptr);
    conv1x1<0><<<dim3(4, 16, 8), 256, 0, stream>>>(tmp, w_proj, out, 128, 256, nullptr);

    dynconv<<<dim3(8, 64, 8), 256, 0, stream>>>(yX, kers, out);
}

// Round 2
// 463.225 us; speedup vs baseline: 3.7993x; 3.7993x over previous
//
#include <hip/hip_runtime.h>
#include <cstddef>

// Problem constants
#define B_   8
#define C4_  256
#define C5_  512
#define OC_  256
#define FR_  128
#define H_   64
#define W_   64
#define HW_  4096

typedef unsigned short u16;
typedef __bf16 bf16x8 __attribute__((ext_vector_type(8)));
typedef float floatx4 __attribute__((ext_vector_type(4)));

__device__ __forceinline__ u16 f2b(float x) {
    unsigned int u = __float_as_uint(x);
    return (u16)((u + 0x7FFFu + ((u >> 16) & 1u)) >> 16);
}

// ---------------------------------------------------------------------------
// Weight packing: w3[oc][c][ky][kx] f32 -> A3[tap][oc][c] bf16
// ---------------------------------------------------------------------------
__global__ __launch_bounds__(256) void pack_w3(const float* __restrict__ in,
                                               u16* __restrict__ out)
{
    int idx = blockIdx.x * 256 + threadIdx.x;       // < 9*256*256 = 589824
    int tap = idx >> 16;
    int r   = idx & 65535;
    int oc  = r >> 8, c = r & 255;
    out[idx] = f2b(in[((size_t)oc * 256 + c) * 9 + tap]);
}

__global__ __launch_bounds__(256) void pack_w1(const float* __restrict__ in,
                                               u16* __restrict__ out)
{
    int idx = blockIdx.x * 256 + threadIdx.x;       // < 256*512
    out[idx] = f2b(in[idx]);
}

// ---------------------------------------------------------------------------
// c4 NCHW f32 -> NHWC bf16.  grid (64 h, 8 b), block 256.
// ---------------------------------------------------------------------------
__global__ __launch_bounds__(256) void pack_c4(const float* __restrict__ in,
                                               u16* __restrict__ out)
{
    __shared__ float sT[64][257];
    const int h = blockIdx.x, b = blockIdx.y, t = threadIdx.x;
    const int w = t & 63, cg = t >> 6;              // cg 0..3
    for (int i = 0; i < 64; ++i) {
        int c = cg * 64 + i;
        sT[w][c] = in[(((size_t)b * 256 + c) * 64 + h) * 64 + w];
    }
    __syncthreads();
    for (int i = 0; i < 16; ++i) {
        int ww = cg * 16 + i;
        int c0 = (t & 63) * 4;
        ushort4 v;
        v.x = f2b(sT[ww][c0]);
        v.y = f2b(sT[ww][c0 + 1]);
        v.z = f2b(sT[ww][c0 + 2]);
        v.w = f2b(sT[ww][c0 + 3]);
        *(ushort4*)&out[(((size_t)b * 64 + h) * 64 + ww) * 256 + c0] = v;
    }
}

// ---------------------------------------------------------------------------
// c5 NCHW f32 (32x32) -> NHWC bf16.  grid (32 h2, 8 b), block 256.
// ---------------------------------------------------------------------------
__global__ __launch_bounds__(256) void pack_c5(const float* __restrict__ in,
                                               u16* __restrict__ out)
{
    __shared__ float sT[32][513];
    const int h2 = blockIdx.x, b = blockIdx.y, t = threadIdx.x;
    const int w = t & 31, cg = t >> 5;              // cg 0..7
    for (int i = 0; i < 64; ++i) {
        int c = cg * 64 + i;
        sT[w][c] = in[(((size_t)b * 512 + c) * 32 + h2) * 32 + w];
    }
    __syncthreads();
    for (int i = 0; i < 16; ++i) {
        int id = i * 256 + t;                        // < 4096
        int ww = id >> 7, c0 = (id & 127) * 4;
        ushort4 v;
        v.x = f2b(sT[ww][c0]);
        v.y = f2b(sT[ww][c0 + 1]);
        v.z = f2b(sT[ww][c0 + 2]);
        v.w = f2b(sT[ww][c0 + 3]);
        *(ushort4*)&out[(((size_t)b * 32 + h2) * 32 + ww) * 512 + c0] = v;
    }
}

// ---------------------------------------------------------------------------
// MFMA implicit-GEMM: fused = conv3x3(c4) + conv1x1(c5_up)
// grid (32 rowpair, 2 octile, 8 b), block 256 = 4 waves (2x2).
// Tile: 128 oc x 128 px (2 rows of 64). K: 256 ch * 9 taps + 512 ch.
// ---------------------------------------------------------------------------
__global__ __launch_bounds__(256) void fuse_mfma(
    const u16* __restrict__ c4t, const u16* __restrict__ c5t,
    const u16* __restrict__ A3, const u16* __restrict__ A1,
    float* __restrict__ fused)
{
    __shared__ u16 sIn[4 * 66 * 40];   // [row 4][col 66][ch 32 pad 40]
    __shared__ u16 sC5[32 * 136];      // [w2 32][ch 128 pad 136]

    const int t   = threadIdx.x;
    const int rp  = blockIdx.x;        // row pair 0..31
    const int oc0 = blockIdx.y * 128;
    const int b   = blockIdx.z;
    const int h0  = rp * 2;

    const int l   = t & 63;
    const int wid = t >> 6;
    const int wm  = wid >> 1;          // 0..1: oc-half
    const int wn  = wid & 1;           // 0..1: row of pair
    const int lr  = l & 15;
    const int ks  = l >> 4;            // k-slice 0..3

    floatx4 acc[4][4];
    #pragma unroll
    for (int m = 0; m < 4; ++m)
        #pragma unroll
        for (int n = 0; n < 4; ++n)
            acc[m][n] = (floatx4){0.f, 0.f, 0.f, 0.f};

    // --- staging precompute: pairs (rr,cl) of the 4x66 halo tile ---
    const int p1 = t;
    const int rr1 = p1 / 66, cl1 = p1 % 66;
    const int gh1 = h0 - 1 + rr1, gw1 = cl1 - 1;
    const bool v1 = (gh1 >= 0 && gh1 < 64 && gw1 >= 0 && gw1 < 64);
    const size_t src1 = ((((size_t)b * 64 + gh1) * 64 + gw1) * 256);
    const int lds1 = p1 * 40;

    const bool has2 = (t < 8);
    const int p2 = t + 256;
    const int rr2 = p2 / 66, cl2 = p2 % 66;
    const int gh2 = h0 - 1 + rr2, gw2 = cl2 - 1;
    const bool v2 = has2 && (gh2 >= 0 && gh2 < 64 && gw2 >= 0 && gw2 < 64);
    const size_t src2 = ((((size_t)b * 64 + gh2) * 64 + gw2) * 256);
    const int lds2 = p2 * 40;

    // pre-zero invalid halo entries once (they are never overwritten)
    {
        int4 z = {0, 0, 0, 0};
        if (!v1) { int4* d = (int4*)&sIn[lds1]; d[0]=z; d[1]=z; d[2]=z; d[3]=z; }
        if (has2 && !v2) { int4* d = (int4*)&sIn[lds2]; d[0]=z; d[1]=z; d[2]=z; d[3]=z; }
    }

    // ------------------- conv3x3 over c4: 8 chunks of 32 ch -------------------
    for (int c0 = 0; c0 < 256; c0 += 32) {
        __syncthreads();
        if (v1) {
            const int4* s = (const int4*)(c4t + src1 + c0);
            int4 a0 = s[0], a1 = s[1], a2 = s[2], a3 = s[3];
            int4* d = (int4*)&sIn[lds1];
            d[0] = a0; d[1] = a1; d[2] = a2; d[3] = a3;
        }
        if (v2) {
            const int4* s = (const int4*)(c4t + src2 + c0);
            int4 a0 = s[0], a1 = s[1], a2 = s[2], a3 = s[3];
            int4* d = (int4*)&sIn[lds2];
            d[0] = a0; d[1] = a1; d[2] = a2; d[3] = a3;
        }
        __syncthreads();

        #pragma unroll
        for (int ky = 0; ky < 3; ++ky) {
            #pragma unroll
            for (int kx = 0; kx < 3; ++kx) {
                const int tap = ky * 3 + kx;
                bf16x8 a[4], bb[4];
                #pragma unroll
                for (int m = 0; m < 4; ++m) {
                    const int oc = oc0 + wm * 64 + m * 16 + lr;
                    a[m] = *(const bf16x8*)(A3 + (((size_t)tap * 256 + oc) * 256 + c0 + ks * 8));
                }
                #pragma unroll
                for (int n = 0; n < 4; ++n) {
                    const int rr = wn + ky;
                    const int cl = n * 16 + lr + kx;
                    bb[n] = *(const bf16x8*)&sIn[(rr * 66 + cl) * 40 + ks * 8];
                }
                #pragma unroll
                for (int m = 0; m < 4; ++m)
                    #pragma unroll
                    for (int n = 0; n < 4; ++n)
                        acc[m][n] = __builtin_amdgcn_mfma_f32_16x16x32_bf16(
                            a[m], bb[n], acc[m][n], 0, 0, 0);
            }
        }
    }

    // ------------------- conv1x1 over c5_up: 4 chunks of 128 ch -------------------
    const int h2 = rp;
    const int w2s = t >> 3, seg = t & 7;
    const size_t src5 = (((size_t)b * 32 + h2) * 32 + w2s) * 512 + seg * 16;
    const int lds5 = w2s * 136 + seg * 16;

    for (int cc0 = 0; cc0 < 512; cc0 += 128) {
        __syncthreads();
        {
            const int4* s = (const int4*)(c5t + src5 + cc0);
            int4 a0 = s[0], a1 = s[1];
            int4* d = (int4*)&sC5[lds5];
            d[0] = a0; d[1] = a1;
        }
        __syncthreads();

        #pragma unroll
        for (int step = 0; step < 4; ++step) {
            const int kk = step * 32;
            bf16x8 a[4], bb[4];
            #pragma unroll
            for (int m = 0; m < 4; ++m) {
                const int oc = oc0 + wm * 64 + m * 16 + lr;
                a[m] = *(const bf16x8*)(A1 + ((size_t)oc * 512 + cc0 + kk + ks * 8));
            }
            #pragma unroll
            for (int n = 0; n < 4; ++n) {
                const int w2 = n * 8 + (lr >> 1);
                bb[n] = *(const bf16x8*)&sC5[w2 * 136 + kk + ks * 8];
            }
            #pragma unroll
            for (int m = 0; m < 4; ++m)
                #pragma unroll
                for (int n = 0; n < 4; ++n)
                    acc[m][n] = __builtin_amdgcn_mfma_f32_16x16x32_bf16(
                        a[m], bb[n], acc[m][n], 0, 0, 0);
        }
    }

    // ------------------- epilogue: fp32 NCHW -------------------
    const int h = h0 + wn;
    #pragma unroll
    for (int m = 0; m < 4; ++m) {
        #pragma unroll
        for (int n = 0; n < 4; ++n) {
            const int w = n * 16 + lr;
            #pragma unroll
            for (int r = 0; r < 4; ++r) {
                const int oc = oc0 + wm * 64 + m * 16 + ks * 4 + r;
                fused[(((size_t)b * 256 + oc) * 64 + h) * 64 + w] = acc[m][n][r];
            }
        }
    }
}

// ---------------------------------------------------------------------------
// Generic tiled 1x1 conv: out[b,oc,hw] = sum_c w[oc,c] * in[b,c,hw]
// grid (Cout/64, H/4, B), block 256.  MODE 1: also accumulate BN sums.
// ---------------------------------------------------------------------------
template <int MODE>
__global__ __launch_bounds__(256) void conv1x1(
    const float* __restrict__ in, const float* __restrict__ w,
    float* __restrict__ out, int Cin, int Cout, float* __restrict__ sums)
{
    __shared__ float sF[8][256];
    __shared__ float sW[8][64];
    __shared__ float lsum[64], lsq[64];

    const int t   = threadIdx.x;
    const int b   = blockIdx.z;
    const int r0  = blockIdx.y * 4;
    const int oc0 = blockIdx.x * 64;

    const int og  = t >> 5;
    const int pg  = t & 31;
    const int ocl = og * 8;
    const int pxb = pg * 8;

    float acc[8][8];
    #pragma unroll
    for (int o = 0; o < 8; ++o)
        #pragma unroll
        for (int p = 0; p < 8; ++p) acc[o][p] = 0.f;

    const float* inb = in + (size_t)b * Cin * HW_ + r0 * W_;

    for (int c0 = 0; c0 < Cin; c0 += 8) {
        __syncthreads();
        for (int idx = t; idx < 2048; idx += 256) {
            int cc = idx >> 8, px = idx & 255;
            sF[cc][px] = inb[(size_t)(c0 + cc) * HW_ + px];
        }
        for (int idx = t; idx < 512; idx += 256) {
            int cc = idx >> 6, o = idx & 63;
            sW[cc][o] = w[(size_t)(oc0 + o) * Cin + c0 + cc];
        }
        __syncthreads();

        #pragma unroll
        for (int cc = 0; cc < 8; ++cc) {
            float f[8], ww[8];
            #pragma unroll
            for (int i = 0; i < 8; ++i) f[i] = sF[cc][pxb + i];
            #pragma unroll
            for (int i = 0; i < 8; ++i) ww[i] = sW[cc][ocl + i];
            #pragma unroll
            for (int o = 0; o < 8; ++o)
                #pragma unroll
                for (int p = 0; p < 8; ++p)
                    acc[o][p] += ww[o] * f[p];
        }
    }

    #pragma unroll
    for (int o = 0; o < 8; ++o) {
        size_t base = ((size_t)b * Cout + oc0 + ocl + o) * HW_ + r0 * W_ + pxb;
        float4 v0 = make_float4(acc[o][0], acc[o][1], acc[o][2], acc[o][3]);
        float4 v1 = make_float4(acc[o][4], acc[o][5], acc[o][6], acc[o][7]);
        *(float4*)&out[base]     = v0;
        *(float4*)&out[base + 4] = v1;
    }

    if (MODE == 1) {
        if (t < 64) { lsum[t] = 0.f; lsq[t] = 0.f; }
        __syncthreads();
        #pragma unroll
        for (int o = 0; o < 8; ++o) {
            float s = 0.f, q = 0.f;
            #pragma unroll
            for (int p = 0; p < 8; ++p) { s += acc[o][p]; q += acc[o][p] * acc[o][p]; }
            atomicAdd(&lsum[ocl + o], s);
            atomicAdd(&lsq[ocl + o], q);
        }
        __syncthreads();
        if (t < 64) {
            atomicAdd(&sums[oc0 + t], lsum[t]);
            atomicAdd(&sums[256 + oc0 + t], lsq[t]);
        }
    }
}

// ---------------------------------------------------------------------------
__global__ void bn_finalize(const float* __restrict__ sums,
                            const float* __restrict__ gamma,
                            const float* __restrict__ beta,
                            float* __restrict__ ab)
{
    int c = threadIdx.x;
    const float n = (float)(B_ * HW_);
    float mu  = sums[c] / n;
    float var = sums[256 + c] / n - mu * mu;
    float a = gamma[c] * rsqrtf(var + 1e-5f);
    ab[c]       = a;
    ab[256 + c] = beta[c] - mu * a;
}

__global__ __launch_bounds__(256) void silu_bn(const float* __restrict__ y,
                                               const float* __restrict__ ab,
                                               float* __restrict__ X)
{
    size_t i = (size_t)blockIdx.x * 256 + threadIdx.x;
    int c = (int)((i >> 10) & 255);
    float a = ab[c], bb = ab[256 + c];
    float4 v = ((const float4*)y)[i];
    float z;
    z = a * v.x + bb; v.x = z / (1.f + __expf(-z));
    z = a * v.y + bb; v.y = z / (1.f + __expf(-z));
    z = a * v.z + bb; v.z = z / (1.f + __expf(-z));
    z = a * v.w + bb; v.w = z / (1.f + __expf(-z));
    ((float4*)X)[i] = v;
}

// ---------------------------------------------------------------------------
__global__ __launch_bounds__(256) void pool_kernel(const float* __restrict__ in,
                                                   float* __restrict__ out,
                                                   int C, int up)
{
    __shared__ float colsum[4][64];
    const int i = blockIdx.x, cg = blockIdx.y, b = blockIdx.z;
    const int t = threadIdx.x;
    const int ch = t >> 6, w = t & 63;
    const int c = cg * 4 + ch;
    const int h0 = (i * 64) / 3, h1 = ((i + 1) * 64 + 2) / 3;
    float s = 0.f;
    for (int h = h0; h < h1; ++h) {
        float v = up ? in[(((size_t)b * C + c) * 32 + (h >> 1)) * 32 + (w >> 1)]
                     : in[(((size_t)b * C + c) * 64 + h) * 64 + w];
        s += v;
    }
    colsum[ch][w] = s;
    __syncthreads();
    if (t < 12) {
        int c2 = t / 3, j = t % 3;
        int w0 = (j * 64) / 3, w1 = ((j + 1) * 64 + 2) / 3;
        float tot = 0.f;
        for (int x = w0; x < w1; ++x) tot += colsum[c2][x];
        out[(((size_t)b * C + cg * 4 + c2) * 3 + i) * 3 + j] =
            tot / (float)((h1 - h0) * (w1 - w0));
    }
}

// ---------------------------------------------------------------------------
__global__ __launch_bounds__(64) void sim_mlp(
    const float* __restrict__ pool4, const float* __restrict__ pool5,
    const float* __restrict__ w4, const float* __restrict__ w5,
    const float* __restrict__ kgw1, const float* __restrict__ kgb1,
    const float* __restrict__ kgw2, const float* __restrict__ kgb2,
    const float* __restrict__ mask, float* __restrict__ kers)
{
    const int r = blockIdx.x, b = blockIdx.y, m = threadIdx.x;
    float p4 = 0.f, p5 = 0.f;
    for (int c = 0; c < C4_; ++c)
        p4 += w4[(size_t)m * C4_ + c] * pool4[((size_t)b * C4_ + c) * 9 + r];
    for (int c = 0; c < C5_; ++c)
        p5 += w5[(size_t)m * C5_ + c] * pool5[((size_t)b * C5_ + c) * 9 + r];
    float v = p4 * p5;
    #pragma unroll
    for (int off = 32; off; off >>= 1) v += __shfl_down(v, off);
    if (m == 0) {
        float g = v * (1.f / (1.f + __expf(-mask[r])));
        float hb[16];
        #pragma unroll
        for (int j = 0; j < 16; ++j) hb[j] = fmaxf(g * kgw1[j] + kgb1[j], 0.f);
        float lg[9], mx = -1e30f;
        #pragma unroll
        for (int k = 0; k < 9; ++k) {
            float s = kgb2[k];
            #pragma unroll
            for (int j = 0; j < 16; ++j) s += kgw2[k * 16 + j] * hb[j];
            lg[k] = s;
            mx = fmaxf(mx, s);
        }
        float den = 0.f;
        #pragma unroll
        for (int k = 0; k < 9; ++k) { lg[k] = __expf(lg[k] - mx); den += lg[k]; }
        float inv = 1.f / den;
        #pragma unroll
        for (int k = 0; k < 9; ++k)
            kers[((size_t)b * 9 + r) * 9 + k] = lg[k] * inv;
    }
}

// ---------------------------------------------------------------------------
__global__ __launch_bounds__(256) void dynconv(const float* __restrict__ X,
                                               const float* __restrict__ kers,
                                               float* __restrict__ out)
{
    __shared__ float sX[4][10][66];
    __shared__ float sK[81];
    const int t = threadIdx.x;
    const int r0 = blockIdx.x * 8, cg = blockIdx.y, b = blockIdx.z;
    const int ch = t >> 6, w = t & 63;
    const int c = cg * 4 + ch;

    for (int idx = t; idx < 2640; idx += 256) {
        int cc = idx / 660, rem = idx % 660, rr = rem / 66, cl = rem % 66;
        int gh = r0 - 1 + rr, gw = cl - 1;
        float v = 0.f;
        if (gh >= 0 && gh < H_ && gw >= 0 && gw < W_)
            v = X[(((size_t)b * 256 + cg * 4 + cc) * H_ + gh) * W_ + gw];
        sX[cc][rr][cl] = v;
    }
    if (t < 81) sK[t] = kers[(size_t)b * 81 + t];
    __syncthreads();

    const int rx = (w * 3) >> 6;
    for (int hh = 0; hh < 8; ++hh) {
        int h = r0 + hh;
        int ry = (h * 3) >> 6;
        const float* kp = &sK[(ry * 3 + rx) * 9];
        float acc = 0.f;
        #pragma unroll
        for (int dy = 0; dy < 3; ++dy)
            #pragma unroll
            for (int dx = 0; dx < 3; ++dx)
                acc += kp[dy * 3 + dx] * sX[ch][hh + dy][w + dx];
        size_t o = (((size_t)b * 256 + c) * H_ + h) * W_ + w;
        out[o] += acc;
    }
}

// ---------------------------------------------------------------------------
// Launch
// ---------------------------------------------------------------------------
extern "C" void kernel_launch(void* const* d_in, const int* in_sizes, int n_in,
                              void* d_out, int out_size, void* d_ws, size_t ws_size,
                              hipStream_t stream)
{
    const float* c4       = (const float*)d_in[0];
    const float* c5       = (const float*)d_in[1];
    const float* w_to_fuse= (const float*)d_in[2];
    const float* bn_gamma = (const float*)d_in[3];
    const float* bn_beta  = (const float*)d_in[4];
    const float* w_c4_proc= (const float*)d_in[5];
    const float* w_conv1  = (const float*)d_in[6];
    const float* w_reshape= (const float*)d_in[7];
    const float* w_proj   = (const float*)d_in[8];
    const float* w_sim4   = (const float*)d_in[9];
    const float* w_sim5   = (const float*)d_in[10];
    const float* kg_w1    = (const float*)d_in[11];
    const float* kg_b1    = (const float*)d_in[12];
    const float* kg_w2    = (const float*)d_in[13];
    const float* kg_b2    = (const float*)d_in[14];
    const float* mask_raw = (const float*)d_in[15];

    float* out = (float*)d_out;
    float* ws  = (float*)d_ws;

    const size_t nF = (size_t)B_ * OC_ * HW_;          // 8388608
    float* fused = ws;
    float* yX    = fused + nF;
    float* tmp   = yX + nF;                            // B*128*4096 floats
    float* pool4 = tmp + (size_t)B_ * FR_ * HW_;
    float* pool5 = pool4 + (size_t)B_ * C4_ * 9;
    float* sums  = pool5 + (size_t)B_ * C5_ * 9;
    float* ab    = sums + 512;
    float* kers  = ab + 512;

    // packed bf16 arrays overlap the yX region (dead until conv1x1<1> writes yX)
    u16* c4t = (u16*)yX;                               // 8388608 u16
    u16* c5t = c4t + (size_t)8388608;                  // 4194304 u16
    u16* A3  = c5t + (size_t)4194304;                  // 589824 u16
    u16* A1  = A3 + (size_t)589824;                    // 131072 u16

    hipMemsetAsync(sums, 0, 512 * sizeof(float), stream);

    pack_w3<<<2304, 256, 0, stream>>>(w_c4_proc, A3);
    pack_w1<<<512, 256, 0, stream>>>(w_conv1, A1);
    pack_c4<<<dim3(64, 8), 256, 0, stream>>>(c4, c4t);
    pack_c5<<<dim3(32, 8), 256, 0, stream>>>(c5, c5t);

    fuse_mfma<<<dim3(32, 2, 8), 256, 0, stream>>>(c4t, c5t, A3, A1, fused);

    conv1x1<1><<<dim3(4, 16, 8), 256, 0, stream>>>(fused, w_to_fuse, yX, 256, 256, sums);

    bn_finalize<<<1, 256, 0, stream>>>(sums, bn_gamma, bn_beta, ab);

    silu_bn<<<8192, 256, 0, stream>>>(yX, ab, yX);

    pool_kernel<<<dim3(3, 64, 8), 256, 0, stream>>>(c4, pool4, 256, 0);
    pool_kernel<<<dim3(3, 128, 8), 256, 0, stream>>>(c5, pool5, 512, 1);

    sim_mlp<<<dim3(9, 8), 64, 0, stream>>>(pool4, pool5, w_sim4, w_sim5,
                                           kg_w1, kg_b1, kg_w2, kg_b2,
                                           mask_raw, kers);

    conv1x1<0><<<dim3(2, 16, 8), 256, 0, stream>>>(fused, w_reshape, tmp, 256, 128, nullptr);
    conv1x1<0><<<dim3(4, 16, 8), 256, 0, stream>>>(tmp, w_proj, out, 128, 256, nullptr);

    dynconv<<<dim3(8, 64, 8), 256, 0, stream>>>(yX, kers, out);
}

// Round 3
// 294.709 us; speedup vs baseline: 5.9718x; 1.5718x over previous
//
#include <hip/hip_runtime.h>
#include <cstddef>

// Problem constants
#define B_   8
#define C4_  256
#define C5_  512
#define OC_  256
#define FR_  128
#define H_   64
#define W_   64
#define HW_  4096

typedef unsigned short u16;
typedef __bf16 bf16x8 __attribute__((ext_vector_type(8)));
typedef float floatx4 __attribute__((ext_vector_type(4)));

__device__ __forceinline__ u16 f2b(float x) {
    unsigned int u = __float_as_uint(x);
    return (u16)((u + 0x7FFFu + ((u >> 16) & 1u)) >> 16);
}

// ---------------------------------------------------------------------------
// Weight packing: w3[oc][c][ky][kx] f32 -> A3[tap][oc][c] bf16
// ---------------------------------------------------------------------------
__global__ __launch_bounds__(256) void pack_w3(const float* __restrict__ in,
                                               u16* __restrict__ out)
{
    int idx = blockIdx.x * 256 + threadIdx.x;       // < 9*256*256 = 589824
    int tap = idx >> 16;
    int r   = idx & 65535;
    int oc  = r >> 8, c = r & 255;
    out[idx] = f2b(in[((size_t)oc * 256 + c) * 9 + tap]);
}

__global__ __launch_bounds__(256) void pack_gen(const float* __restrict__ in,
                                                u16* __restrict__ out, int n)
{
    int i = blockIdx.x * 256 + threadIdx.x;
    if (i < n) out[i] = f2b(in[i]);
}

// W_eff[oc][c] = sum_f w_proj[oc][f] * w_reshape[f][c]  (256x256, K=128)
__global__ __launch_bounds__(256) void weff_kernel(const float* __restrict__ wp,
                                                   const float* __restrict__ wr,
                                                   u16* __restrict__ weff)
{
    const int oc = blockIdx.x, c = threadIdx.x;
    float s = 0.f;
    for (int f = 0; f < 128; ++f)
        s += wp[oc * 128 + f] * wr[f * 256 + c];
    weff[oc * 256 + c] = f2b(s);
}

// ---------------------------------------------------------------------------
// c4 NCHW f32 -> NHWC bf16.  grid (64 h, 8 b), block 256.
// ---------------------------------------------------------------------------
__global__ __launch_bounds__(256) void pack_c4(const float* __restrict__ in,
                                               u16* __restrict__ out)
{
    __shared__ float sT[64][257];
    const int h = blockIdx.x, b = blockIdx.y, t = threadIdx.x;
    const int w = t & 63, cg = t >> 6;              // cg 0..3
    for (int i = 0; i < 64; ++i) {
        int c = cg * 64 + i;
        sT[w][c] = in[(((size_t)b * 256 + c) * 64 + h) * 64 + w];
    }
    __syncthreads();
    for (int i = 0; i < 16; ++i) {
        int ww = cg * 16 + i;
        int c0 = (t & 63) * 4;
        ushort4 v;
        v.x = f2b(sT[ww][c0]);
        v.y = f2b(sT[ww][c0 + 1]);
        v.z = f2b(sT[ww][c0 + 2]);
        v.w = f2b(sT[ww][c0 + 3]);
        *(ushort4*)&out[(((size_t)b * 64 + h) * 64 + ww) * 256 + c0] = v;
    }
}

// ---------------------------------------------------------------------------
// c5 NCHW f32 (32x32) -> NHWC bf16.  grid (32 h2, 8 b), block 256.
// ---------------------------------------------------------------------------
__global__ __launch_bounds__(256) void pack_c5(const float* __restrict__ in,
                                               u16* __restrict__ out)
{
    __shared__ float sT[32][513];
    const int h2 = blockIdx.x, b = blockIdx.y, t = threadIdx.x;
    const int w = t & 31, cg = t >> 5;              // cg 0..7
    for (int i = 0; i < 64; ++i) {
        int c = cg * 64 + i;
        sT[w][c] = in[(((size_t)b * 512 + c) * 32 + h2) * 32 + w];
    }
    __syncthreads();
    for (int i = 0; i < 16; ++i) {
        int id = i * 256 + t;                        // < 4096
        int ww = id >> 7, c0 = (id & 127) * 4;
        ushort4 v;
        v.x = f2b(sT[ww][c0]);
        v.y = f2b(sT[ww][c0 + 1]);
        v.z = f2b(sT[ww][c0 + 2]);
        v.w = f2b(sT[ww][c0 + 3]);
        *(ushort4*)&out[(((size_t)b * 32 + h2) * 32 + ww) * 512 + c0] = v;
    }
}

// ---------------------------------------------------------------------------
// MFMA implicit-GEMM: fusedb(bf16 NHWC) = conv3x3(c4) + conv1x1(c5_up)
// grid (32 rowpair, 2 octile, 8 b), block 256 = 4 waves (2x2).
// ---------------------------------------------------------------------------
__global__ __launch_bounds__(256) void fuse_mfma(
    const u16* __restrict__ c4t, const u16* __restrict__ c5t,
    const u16* __restrict__ A3, const u16* __restrict__ A1,
    u16* __restrict__ fusedb)
{
    __shared__ u16 sIn[4 * 66 * 40];   // [row 4][col 66][ch 32 pad 40]
    __shared__ u16 sC5[32 * 136];      // [w2 32][ch 128 pad 136]

    const int t   = threadIdx.x;
    const int rp  = blockIdx.x;        // row pair 0..31
    const int oc0 = blockIdx.y * 128;
    const int b   = blockIdx.z;
    const int h0  = rp * 2;

    const int l   = t & 63;
    const int wid = t >> 6;
    const int wm  = wid >> 1;          // 0..1: oc-half
    const int wn  = wid & 1;           // 0..1: row of pair
    const int lr  = l & 15;
    const int ks  = l >> 4;            // k-slice 0..3

    floatx4 acc[4][4];
    #pragma unroll
    for (int m = 0; m < 4; ++m)
        #pragma unroll
        for (int n = 0; n < 4; ++n)
            acc[m][n] = (floatx4){0.f, 0.f, 0.f, 0.f};

    const int p1 = t;
    const int rr1 = p1 / 66, cl1 = p1 % 66;
    const int gh1 = h0 - 1 + rr1, gw1 = cl1 - 1;
    const bool v1 = (gh1 >= 0 && gh1 < 64 && gw1 >= 0 && gw1 < 64);
    const size_t src1 = ((((size_t)b * 64 + gh1) * 64 + gw1) * 256);
    const int lds1 = p1 * 40;

    const bool has2 = (t < 8);
    const int p2 = t + 256;
    const int rr2 = p2 / 66, cl2 = p2 % 66;
    const int gh2 = h0 - 1 + rr2, gw2 = cl2 - 1;
    const bool v2 = has2 && (gh2 >= 0 && gh2 < 64 && gw2 >= 0 && gw2 < 64);
    const size_t src2 = ((((size_t)b * 64 + gh2) * 64 + gw2) * 256);
    const int lds2 = p2 * 40;

    {
        int4 z = {0, 0, 0, 0};
        if (!v1) { int4* d = (int4*)&sIn[lds1]; d[0]=z; d[1]=z; d[2]=z; d[3]=z; }
        if (has2 && !v2) { int4* d = (int4*)&sIn[lds2]; d[0]=z; d[1]=z; d[2]=z; d[3]=z; }
    }

    // ------------------- conv3x3 over c4: 8 chunks of 32 ch -------------------
    for (int c0 = 0; c0 < 256; c0 += 32) {
        __syncthreads();
        if (v1) {
            const int4* s = (const int4*)(c4t + src1 + c0);
            int4 a0 = s[0], a1 = s[1], a2 = s[2], a3 = s[3];
            int4* d = (int4*)&sIn[lds1];
            d[0] = a0; d[1] = a1; d[2] = a2; d[3] = a3;
        }
        if (v2) {
            const int4* s = (const int4*)(c4t + src2 + c0);
            int4 a0 = s[0], a1 = s[1], a2 = s[2], a3 = s[3];
            int4* d = (int4*)&sIn[lds2];
            d[0] = a0; d[1] = a1; d[2] = a2; d[3] = a3;
        }
        __syncthreads();

        #pragma unroll
        for (int ky = 0; ky < 3; ++ky) {
            #pragma unroll
            for (int kx = 0; kx < 3; ++kx) {
                const int tap = ky * 3 + kx;
                bf16x8 a[4], bb[4];
                #pragma unroll
                for (int m = 0; m < 4; ++m) {
                    const int oc = oc0 + wm * 64 + m * 16 + lr;
                    a[m] = *(const bf16x8*)(A3 + (((size_t)tap * 256 + oc) * 256 + c0 + ks * 8));
                }
                #pragma unroll
                for (int n = 0; n < 4; ++n) {
                    const int rr = wn + ky;
                    const int cl = n * 16 + lr + kx;
                    bb[n] = *(const bf16x8*)&sIn[(rr * 66 + cl) * 40 + ks * 8];
                }
                #pragma unroll
                for (int m = 0; m < 4; ++m)
                    #pragma unroll
                    for (int n = 0; n < 4; ++n)
                        acc[m][n] = __builtin_amdgcn_mfma_f32_16x16x32_bf16(
                            a[m], bb[n], acc[m][n], 0, 0, 0);
            }
        }
    }

    // ------------------- conv1x1 over c5_up: 4 chunks of 128 ch -------------------
    const int h2 = rp;
    const int w2s = t >> 3, seg = t & 7;
    const size_t src5 = (((size_t)b * 32 + h2) * 32 + w2s) * 512 + seg * 16;
    const int lds5 = w2s * 136 + seg * 16;

    for (int cc0 = 0; cc0 < 512; cc0 += 128) {
        __syncthreads();
        {
            const int4* s = (const int4*)(c5t + src5 + cc0);
            int4 a0 = s[0], a1 = s[1];
            int4* d = (int4*)&sC5[lds5];
            d[0] = a0; d[1] = a1;
        }
        __syncthreads();

        #pragma unroll
        for (int step = 0; step < 4; ++step) {
            const int kk = step * 32;
            bf16x8 a[4], bb[4];
            #pragma unroll
            for (int m = 0; m < 4; ++m) {
                const int oc = oc0 + wm * 64 + m * 16 + lr;
                a[m] = *(const bf16x8*)(A1 + ((size_t)oc * 512 + cc0 + kk + ks * 8));
            }
            #pragma unroll
            for (int n = 0; n < 4; ++n) {
                const int w2 = n * 8 + (lr >> 1);
                bb[n] = *(const bf16x8*)&sC5[w2 * 136 + kk + ks * 8];
            }
            #pragma unroll
            for (int m = 0; m < 4; ++m)
                #pragma unroll
                for (int n = 0; n < 4; ++n)
                    acc[m][n] = __builtin_amdgcn_mfma_f32_16x16x32_bf16(
                        a[m], bb[n], acc[m][n], 0, 0, 0);
        }
    }

    // ------------------- epilogue: bf16 NHWC -------------------
    const int h = h0 + wn;
    #pragma unroll
    for (int n = 0; n < 4; ++n) {
        const int w = n * 16 + lr;
        const size_t base = (((size_t)b * 64 + h) * 64 + w) * 256;
        #pragma unroll
        for (int m = 0; m < 4; ++m) {
            const int oc = oc0 + wm * 64 + m * 16 + ks * 4;
            ushort4 v;
            v.x = f2b(acc[m][n][0]);
            v.y = f2b(acc[m][n][1]);
            v.z = f2b(acc[m][n][2]);
            v.w = f2b(acc[m][n][3]);
            *(ushort4*)&fusedb[base + oc] = v;
        }
    }
}

// ---------------------------------------------------------------------------
// Concatenated 1x1 GEMM from fusedb (bf16 NHWC), no LDS:
//   oct 0,1: y  = Wtf  @ fused  (fp32 NCHW) + BN sums
//   oct 2,3: out = Weff @ fused (fp32 NCHW)
// grid (256 pxtiles, 4 octiles), block 256 = 4 waves (2x2).
// ---------------------------------------------------------------------------
__global__ __launch_bounds__(256) void gemm_cat(
    const u16* __restrict__ Bx, const u16* __restrict__ Wtf,
    const u16* __restrict__ Weff,
    float* __restrict__ y, float* __restrict__ out, float* __restrict__ sums)
{
    __shared__ float lsum[128], lsq[128];

    const int t = threadIdx.x;
    const int pxt = blockIdx.x;
    const int oct = blockIdx.y;
    const bool isY = (oct < 2);
    const u16* W = isY ? Wtf : Weff;
    const int oc0 = (oct & 1) * 128;
    const size_t pxg0 = (size_t)pxt * 128;

    const int l = t & 63, wid = t >> 6;
    const int wm = wid >> 1, wn = wid & 1;
    const int lr = l & 15, ks = l >> 4;

    floatx4 acc[4][4];
    #pragma unroll
    for (int m = 0; m < 4; ++m)
        #pragma unroll
        for (int n = 0; n < 4; ++n)
            acc[m][n] = (floatx4){0.f, 0.f, 0.f, 0.f};

    const u16* Wp = W + (size_t)(oc0 + wm * 64 + lr) * 256 + ks * 8;
    const u16* Bp = Bx + (pxg0 + wn * 64 + lr) * 256 + ks * 8;

    for (int c0 = 0; c0 < 256; c0 += 32) {
        bf16x8 a[4], bb[4];
        #pragma unroll
        for (int m = 0; m < 4; ++m)
            a[m] = *(const bf16x8*)(Wp + (size_t)m * 16 * 256 + c0);
        #pragma unroll
        for (int n = 0; n < 4; ++n)
            bb[n] = *(const bf16x8*)(Bp + (size_t)n * 16 * 256 + c0);
        #pragma unroll
        for (int m = 0; m < 4; ++m)
            #pragma unroll
            for (int n = 0; n < 4; ++n)
                acc[m][n] = __builtin_amdgcn_mfma_f32_16x16x32_bf16(
                    a[m], bb[n], acc[m][n], 0, 0, 0);
    }

    // epilogue: fp32 NCHW
    const int b = pxt >> 5;
    const int pxl = (pxt & 31) * 128;
    float* dst = isY ? y : out;
    #pragma unroll
    for (int m = 0; m < 4; ++m) {
        #pragma unroll
        for (int n = 0; n < 4; ++n) {
            const int px = pxl + wn * 64 + n * 16 + lr;
            #pragma unroll
            for (int r = 0; r < 4; ++r) {
                const int oc = oc0 + wm * 64 + m * 16 + ks * 4 + r;
                dst[((size_t)b * 256 + oc) * 4096 + px] = acc[m][n][r];
            }
        }
    }

    if (isY) {
        if (t < 128) { lsum[t] = 0.f; lsq[t] = 0.f; }
        __syncthreads();
        #pragma unroll
        for (int m = 0; m < 4; ++m) {
            #pragma unroll
            for (int r = 0; r < 4; ++r) {
                float s = 0.f, q = 0.f;
                #pragma unroll
                for (int n = 0; n < 4; ++n) {
                    float v = acc[m][n][r];
                    s += v; q += v * v;
                }
                #pragma unroll
                for (int off = 1; off < 16; off <<= 1) {
                    s += __shfl_xor(s, off);
                    q += __shfl_xor(q, off);
                }
                if (lr == 0) {
                    const int ocl = wm * 64 + m * 16 + ks * 4 + r;
                    atomicAdd(&lsum[ocl], s);
                    atomicAdd(&lsq[ocl], q);
                }
            }
        }
        __syncthreads();
        if (t < 128) {
            atomicAdd(&sums[oc0 + t], lsum[t]);
            atomicAdd(&sums[256 + oc0 + t], lsq[t]);
        }
    }
}

// ---------------------------------------------------------------------------
__global__ void bn_finalize(const float* __restrict__ sums,
                            const float* __restrict__ gamma,
                            const float* __restrict__ beta,
                            float* __restrict__ ab)
{
    int c = threadIdx.x;
    const float n = (float)(B_ * HW_);
    float mu  = sums[c] / n;
    float var = sums[256 + c] / n - mu * mu;
    float a = gamma[c] * rsqrtf(var + 1e-5f);
    ab[c]       = a;
    ab[256 + c] = beta[c] - mu * a;
}

// ---------------------------------------------------------------------------
__global__ __launch_bounds__(256) void pool_kernel(const float* __restrict__ in,
                                                   float* __restrict__ out,
                                                   int C, int up)
{
    __shared__ float colsum[4][64];
    const int i = blockIdx.x, cg = blockIdx.y, b = blockIdx.z;
    const int t = threadIdx.x;
    const int ch = t >> 6, w = t & 63;
    const int c = cg * 4 + ch;
    const int h0 = (i * 64) / 3, h1 = ((i + 1) * 64 + 2) / 3;
    float s = 0.f;
    for (int h = h0; h < h1; ++h) {
        float v = up ? in[(((size_t)b * C + c) * 32 + (h >> 1)) * 32 + (w >> 1)]
                     : in[(((size_t)b * C + c) * 64 + h) * 64 + w];
        s += v;
    }
    colsum[ch][w] = s;
    __syncthreads();
    if (t < 12) {
        int c2 = t / 3, j = t % 3;
        int w0 = (j * 64) / 3, w1 = ((j + 1) * 64 + 2) / 3;
        float tot = 0.f;
        for (int x = w0; x < w1; ++x) tot += colsum[c2][x];
        out[(((size_t)b * C + cg * 4 + c2) * 3 + i) * 3 + j] =
            tot / (float)((h1 - h0) * (w1 - w0));
    }
}

// ---------------------------------------------------------------------------
__global__ __launch_bounds__(64) void sim_mlp(
    const float* __restrict__ pool4, const float* __restrict__ pool5,
    const float* __restrict__ w4, const float* __restrict__ w5,
    const float* __restrict__ kgw1, const float* __restrict__ kgb1,
    const float* __restrict__ kgw2, const float* __restrict__ kgb2,
    const float* __restrict__ mask, float* __restrict__ kers)
{
    const int r = blockIdx.x, b = blockIdx.y, m = threadIdx.x;
    float p4 = 0.f, p5 = 0.f;
    for (int c = 0; c < C4_; ++c)
        p4 += w4[(size_t)m * C4_ + c] * pool4[((size_t)b * C4_ + c) * 9 + r];
    for (int c = 0; c < C5_; ++c)
        p5 += w5[(size_t)m * C5_ + c] * pool5[((size_t)b * C5_ + c) * 9 + r];
    float v = p4 * p5;
    #pragma unroll
    for (int off = 32; off; off >>= 1) v += __shfl_down(v, off);
    if (m == 0) {
        float g = v * (1.f / (1.f + __expf(-mask[r])));
        float hb[16];
        #pragma unroll
        for (int j = 0; j < 16; ++j) hb[j] = fmaxf(g * kgw1[j] + kgb1[j], 0.f);
        float lg[9], mx = -1e30f;
        #pragma unroll
        for (int k = 0; k < 9; ++k) {
            float s = kgb2[k];
            #pragma unroll
            for (int j = 0; j < 16; ++j) s += kgw2[k * 16 + j] * hb[j];
            lg[k] = s;
            mx = fmaxf(mx, s);
        }
        float den = 0.f;
        #pragma unroll
        for (int k = 0; k < 9; ++k) { lg[k] = __expf(lg[k] - mx); den += lg[k]; }
        float inv = 1.f / den;
        #pragma unroll
        for (int k = 0; k < 9; ++k)
            kers[((size_t)b * 9 + r) * 9 + k] = lg[k] * inv;
    }
}

// ---------------------------------------------------------------------------
// Dynamic 3x3 per-region conv with fused BN+SiLU on the fly:
//   X = silu(a*y + b) staged in LDS (halo zeros stay zero),
//   out += sum_k X[b,c,h+dy-1,w+dx-1] * K[b,region,k]
// grid (H/8, 256/4, B), block 256 = 4ch x 64w
// ---------------------------------------------------------------------------
__global__ __launch_bounds__(256) void dynconv_bn(const float* __restrict__ yin,
                                                  const float* __restrict__ ab,
                                                  const float* __restrict__ kers,
                                                  float* __restrict__ out)
{
    __shared__ float sX[4][10][66];
    __shared__ float sK[81];
    __shared__ float sAB[8];
    const int t = threadIdx.x;
    const int r0 = blockIdx.x * 8, cg = blockIdx.y, b = blockIdx.z;
    const int ch = t >> 6, w = t & 63;
    const int c = cg * 4 + ch;

    if (t < 4)      sAB[t] = ab[cg * 4 + t];
    else if (t < 8) sAB[t] = ab[252 + cg * 4 + t];   // 256 + cg*4 + (t-4)
    if (t < 81) sK[t] = kers[(size_t)b * 81 + t];
    __syncthreads();

    for (int idx = t; idx < 2640; idx += 256) {
        int cc = idx / 660, rem = idx % 660, rr = rem / 66, cl = rem % 66;
        int gh = r0 - 1 + rr, gw = cl - 1;
        float v = 0.f;
        if (gh >= 0 && gh < H_ && gw >= 0 && gw < W_) {
            float yv = yin[(((size_t)b * 256 + cg * 4 + cc) * H_ + gh) * W_ + gw];
            float z = fmaf(sAB[cc], yv, sAB[4 + cc]);
            v = z / (1.f + __expf(-z));
        }
        sX[cc][rr][cl] = v;
    }
    __syncthreads();

    const int rx = (w * 3) >> 6;
    for (int hh = 0; hh < 8; ++hh) {
        int h = r0 + hh;
        int ry = (h * 3) >> 6;
        const float* kp = &sK[(ry * 3 + rx) * 9];
        float acc = 0.f;
        #pragma unroll
        for (int dy = 0; dy < 3; ++dy)
            #pragma unroll
            for (int dx = 0; dx < 3; ++dx)
                acc += kp[dy * 3 + dx] * sX[ch][hh + dy][w + dx];
        size_t o = (((size_t)b * 256 + c) * H_ + h) * W_ + w;
        out[o] += acc;
    }
}

// ---------------------------------------------------------------------------
// Launch
// ---------------------------------------------------------------------------
extern "C" void kernel_launch(void* const* d_in, const int* in_sizes, int n_in,
                              void* d_out, int out_size, void* d_ws, size_t ws_size,
                              hipStream_t stream)
{
    const float* c4       = (const float*)d_in[0];
    const float* c5       = (const float*)d_in[1];
    const float* w_to_fuse= (const float*)d_in[2];
    const float* bn_gamma = (const float*)d_in[3];
    const float* bn_beta  = (const float*)d_in[4];
    const float* w_c4_proc= (const float*)d_in[5];
    const float* w_conv1  = (const float*)d_in[6];
    const float* w_reshape= (const float*)d_in[7];
    const float* w_proj   = (const float*)d_in[8];
    const float* w_sim4   = (const float*)d_in[9];
    const float* w_sim5   = (const float*)d_in[10];
    const float* kg_w1    = (const float*)d_in[11];
    const float* kg_b1    = (const float*)d_in[12];
    const float* kg_w2    = (const float*)d_in[13];
    const float* kg_b2    = (const float*)d_in[14];
    const float* mask_raw = (const float*)d_in[15];

    float* out = (float*)d_out;

    // workspace layout
    float* y     = (float*)d_ws;                       // 8388608 f32
    u16*   fusedb= (u16*)(y + 8388608);                // 8388608 u16
    u16*   c4t   = fusedb + 8388608;                   // 8388608 u16
    u16*   c5t   = c4t + 8388608;                      // 4194304 u16
    u16*   A3    = c5t + 4194304;                      // 589824 u16
    u16*   A1    = A3 + 589824;                        // 131072 u16
    u16*   Wtf   = A1 + 131072;                        // 65536 u16
    u16*   Weff  = Wtf + 65536;                        // 65536 u16
    float* pool4 = (float*)(Weff + 65536);             // 18432 f32
    float* pool5 = pool4 + 18432;                      // 36864 f32
    float* sums  = pool5 + 36864;                      // 512
    float* ab    = sums + 512;                         // 512
    float* kers  = ab + 512;                           // 648

    hipMemsetAsync(sums, 0, 512 * sizeof(float), stream);

    pack_w3<<<2304, 256, 0, stream>>>(w_c4_proc, A3);
    pack_gen<<<512, 256, 0, stream>>>(w_conv1, A1, 131072);
    pack_gen<<<256, 256, 0, stream>>>(w_to_fuse, Wtf, 65536);
    weff_kernel<<<256, 256, 0, stream>>>(w_proj, w_reshape, Weff);
    pack_c4<<<dim3(64, 8), 256, 0, stream>>>(c4, c4t);
    pack_c5<<<dim3(32, 8), 256, 0, stream>>>(c5, c5t);

    fuse_mfma<<<dim3(32, 2, 8), 256, 0, stream>>>(c4t, c5t, A3, A1, fusedb);

    gemm_cat<<<dim3(256, 4), 256, 0, stream>>>(fusedb, Wtf, Weff, y, out, sums);

    bn_finalize<<<1, 256, 0, stream>>>(sums, bn_gamma, bn_beta, ab);

    pool_kernel<<<dim3(3, 64, 8), 256, 0, stream>>>(c4, pool4, 256, 0);
    pool_kernel<<<dim3(3, 128, 8), 256, 0, stream>>>(c5, pool5, 512, 1);

    sim_mlp<<<dim3(9, 8), 64, 0, stream>>>(pool4, pool5, w_sim4, w_sim5,
                                           kg_w1, kg_b1, kg_w2, kg_b2,
                                           mask_raw, kers);

    dynconv_bn<<<dim3(8, 64, 8), 256, 0, stream>>>(y, ab, kers, out);
}